// Round 6
// baseline (783.501 us; speedup 1.0000x reference)
//
#include <hip/hip_runtime.h>
#include <hip/hip_bf16.h>
#include <cstdint>
#include <cstddef>

// ---------------- problem constants ----------------
#define TOKENS   8192          // B*S
#define HID      2048
#define LAT      512
#define LAT2     1024
#define GCOLS    2048          // 4 gates * LAT (packed col = 4*l + g)
#define STEPS    8
#define DEC_ELEMS (TOKENS*HID)
#define HSZ      (TOKENS*LAT)  // elements per latent buffer

typedef __attribute__((ext_vector_type(8))) __bf16 bf16x8;
typedef __attribute__((ext_vector_type(4))) float  f32x4;

// ---------------- helpers ----------------
__device__ __forceinline__ unsigned short f32_to_bf16_rne(float f) {
  unsigned int u = __float_as_uint(f);
  unsigned int r = (u + 0x7FFFu + ((u >> 16) & 1u)) >> 16;
  return (unsigned short)r;
}
__device__ __forceinline__ float bf16_to_f32(unsigned short u) {
  return __uint_as_float(((unsigned int)u) << 16);
}

__device__ __forceinline__ float sigmoidf_(float x) {
  if (x >= 0.f) { float e = __expf(-x); return 1.f / (1.f + e); }
  float e = __expf(x); return e / (1.f + e);
}
__device__ __forceinline__ float tanhf_(float x) {
  float ax = fabsf(x);
  float e  = __expf(-2.f * ax);
  float t  = (1.f - e) / (1.f + e);
  return copysignf(t, x);
}

__device__ __forceinline__ void gl_lds16(const void* g, void* l) {
  __builtin_amdgcn_global_load_lds(
      (const __attribute__((address_space(1))) void*)g,
      (__attribute__((address_space(3))) void*)l, 16, 0, 0);
}

// ---------------- prep kernels ----------------
__global__ void k_prep(const float* __restrict__ hs,  const float* __restrict__ We1,
                       const float* __restrict__ We2, const float* __restrict__ Wd1,
                       const float* __restrict__ Wd2,
                       unsigned short* __restrict__ A0,   unsigned short* __restrict__ We1b,
                       unsigned short* __restrict__ We2b, unsigned short* __restrict__ Wd1b,
                       unsigned short* __restrict__ Wd2b) {
  const int total = 5505024;   // float4 count
  int i = blockIdx.x * blockDim.x + threadIdx.x;
  int stride = gridDim.x * blockDim.x;
  for (; i < total; i += stride) {
    const float* s; unsigned short* d; int j;
    if (i < 4194304)      { s = hs;  d = A0;   j = i; }
    else if (i < 4718592) { s = We1; d = We1b; j = i - 4194304; }
    else if (i < 4849664) { s = We2; d = We2b; j = i - 4718592; }
    else if (i < 4980736) { s = Wd1; d = Wd1b; j = i - 4849664; }
    else                  { s = Wd2; d = Wd2b; j = i - 4980736; }
    float4 v = ((const float4*)s)[j];
    ushort4 o;
    o.x = f32_to_bf16_rne(v.x);
    o.y = f32_to_bf16_rne(v.y);
    o.z = f32_to_bf16_rne(v.z);
    o.w = f32_to_bf16_rne(v.w);
    ((ushort4*)d)[j] = o;
  }
}

// Pack GRU weights: output row gc = 4*l + g, g in {0:r-sum, 1:z-sum, 2:i_n, 3:h_n}
__global__ void k_gru_pack(const float* __restrict__ wih, const float* __restrict__ whh,
                           const float* __restrict__ bih, const float* __restrict__ bhh,
                           unsigned short* __restrict__ Wg, float* __restrict__ biasg) {
  int gc = blockIdx.x;
  int l  = gc >> 2;
  int g  = gc & 3;
  int row = (g == 0) ? l : (g == 1) ? (512 + l) : (1024 + l);
  for (int c = threadIdx.x; c < LAT; c += blockDim.x) {
    float v;
    if (g <= 1)      v = wih[row * LAT + c] + whh[row * LAT + c];
    else if (g == 2) v = wih[row * LAT + c];
    else             v = whh[row * LAT + c];
    Wg[(size_t)gc * LAT + c] = f32_to_bf16_rne(v);
  }
  if (threadIdx.x == 0) {
    float b;
    if (g <= 1)      b = bih[row] + bhh[row];
    else if (g == 2) b = bih[row];
    else             b = bhh[row];
    biasg[gc] = b;
  }
}

// =======================================================================
// 128x128 2-barrier kernel (E1, E2, D1)
// =======================================================================
#define MWG 128
#define NWG 128
#define KTILE 64

template <int EPI>   // 0: relu->bf16, 1: bf16
__global__ __launch_bounds__(256)
void gemm_bt(const unsigned short* __restrict__ A,
             const unsigned short* __restrict__ W,
             const float* __restrict__ bias,
             int K, int N,
             unsigned short* __restrict__ outB) {
  __shared__ __align__(16) char smem[2 * MWG * KTILE * 2];
  unsigned short* As = (unsigned short*)smem;
  unsigned short* Bs = As + MWG * KTILE;

  const int tid  = threadIdx.x;
  const int lane = tid & 63;
  const int wv   = tid >> 6;
  const int wr   = wv >> 1;
  const int wc   = wv & 1;
  const int m0   = blockIdx.x * MWG;
  const int n0   = blockIdx.y * NWG;

  const int lr = lane & 15;
  const int lq = lane >> 4;
  const int srow = lane >> 3;
  const int scol = (lane & 7) * 8;

  f32x4 acc[4][4];
#pragma unroll
  for (int i = 0; i < 4; ++i)
#pragma unroll
    for (int j = 0; j < 4; ++j) acc[i][j] = (f32x4){0.f, 0.f, 0.f, 0.f};

  const unsigned short* Ab = A + (size_t)m0 * K;
  const unsigned short* Wb = W + (size_t)n0 * K;

  const int KT = K / KTILE;
  for (int kt = 0; kt < KT; ++kt) {
    const int k0 = kt * KTILE;
#pragma unroll
    for (int q = 0; q < 4; ++q) {
      int row = 32 * wv + 8 * q + srow;
      gl_lds16(Ab + (size_t)row * K + k0 + scol, As + (32 * wv + 8 * q) * KTILE);
      gl_lds16(Wb + (size_t)row * K + k0 + scol, Bs + (32 * wv + 8 * q) * KTILE);
    }
    __syncthreads();
#pragma unroll
    for (int kk = 0; kk < KTILE; kk += 32) {
      bf16x8 af[4], bf[4];
#pragma unroll
      for (int i = 0; i < 4; ++i)
        af[i] = *(const bf16x8*)(As + (wr * 64 + i * 16 + lr) * KTILE + kk + lq * 8);
#pragma unroll
      for (int j = 0; j < 4; ++j)
        bf[j] = *(const bf16x8*)(Bs + (wc * 64 + j * 16 + lr) * KTILE + kk + lq * 8);
#pragma unroll
      for (int i = 0; i < 4; ++i)
#pragma unroll
        for (int j = 0; j < 4; ++j)
          acc[i][j] = __builtin_amdgcn_mfma_f32_16x16x32_bf16(af[i], bf[j], acc[i][j], 0, 0, 0);
    }
    __syncthreads();
  }

  float bj[4];
#pragma unroll
  for (int j = 0; j < 4; ++j) bj[j] = bias[n0 + wc * 64 + j * 16 + lr];
#pragma unroll
  for (int i = 0; i < 4; ++i) {
#pragma unroll
    for (int ii = 0; ii < 4; ++ii) {
      int row = m0 + wr * 64 + i * 16 + 4 * lq + ii;
#pragma unroll
      for (int j = 0; j < 4; ++j) {
        int col = n0 + wc * 64 + j * 16 + lr;
        float v = acc[i][j][ii] + bj[j];
        if constexpr (EPI == 0) {
          outB[(size_t)row * N + col] = f32_to_bf16_rne(fmaxf(v, 0.f));
        } else {
          outB[(size_t)row * N + col] = f32_to_bf16_rne(v);
        }
      }
    }
  }
}

// =======================================================================
// 256x256 8-phase pipeline pieces
// =======================================================================

#define WAIT_LGKM0() asm volatile("s_waitcnt lgkmcnt(0)" ::: "memory")
#define WAIT_VM(n)   asm volatile("s_waitcnt vmcnt(" #n ")" ::: "memory")

#define LOAD_A(buf, mh) { \
  const int baseA = (buf)*65536 + wm*16384; \
  _Pragma("unroll") for (int m4 = 0; m4 < 4; ++m4) \
  _Pragma("unroll") for (int kki = 0; kki < 2; ++kki) { \
    int rl = (mh)*64 + m4*16 + lr; \
    int off = (rl*128 + kki*64 + lq*16) ^ ((rl & 7) << 4); \
    aR[mh][m4][kki] = *(const bf16x8*)(lds_ + baseA + off); } }

#define LOAD_B(buf, nh) { \
  const int baseB = (buf)*65536 + 32768 + (wn >> 1)*16384; \
  _Pragma("unroll") for (int n2 = 0; n2 < 2; ++n2) \
  _Pragma("unroll") for (int kki = 0; kki < 2; ++kki) { \
    int rl = (wn & 1)*64 + ((nh)*2 + n2)*16 + lr; \
    int off = (rl*128 + kki*64 + lq*16) ^ ((rl & 7) << 4); \
    bR[nh][n2][kki] = *(const bf16x8*)(lds_ + baseB + off); } }

#define STAGE_A(buf, half, kt) { \
  const unsigned short* gp = A + (size_t)(m0 + (half)*128 + rr8)*K + (size_t)(kt)*64 + cc8; \
  char* dp = lds_ + (buf)*65536 + (half)*16384 + (wv << 10); \
  gl_lds16(gp, dp); \
  gl_lds16(gp + (size_t)64*K, dp + 8192); }

#define STAGE_B(buf, half, kt) { \
  const unsigned short* gp = W + (size_t)(n0 + (half)*128 + rr8)*K + (size_t)(kt)*64 + cc8; \
  char* dp = lds_ + (buf)*65536 + 32768 + (half)*16384 + (wv << 10); \
  gl_lds16(gp, dp); \
  gl_lds16(gp + (size_t)64*K, dp + 8192); }

#define MFMAQ(mh, nh) \
  _Pragma("unroll") for (int kki = 0; kki < 2; ++kki) \
  _Pragma("unroll") for (int n2 = 0; n2 < 2; ++n2) \
  _Pragma("unroll") for (int m4 = 0; m4 < 4; ++m4) \
    acc[(mh)*4 + m4][(nh)*2 + n2] = __builtin_amdgcn_mfma_f32_16x16x32_bf16( \
        aR[mh][m4][kki], bR[nh][n2][kki], acc[(mh)*4 + m4][(nh)*2 + n2], 0, 0, 0);

#define PH_CORE(mh, nh) \
  __builtin_amdgcn_s_barrier(); \
  WAIT_LGKM0(); \
  __builtin_amdgcn_sched_barrier(0); \
  __builtin_amdgcn_s_setprio(1); \
  MFMAQ(mh, nh); \
  __builtin_amdgcn_sched_barrier(0); \
  __builtin_amdgcn_s_setprio(0);

#define PH_BAR() __builtin_amdgcn_s_barrier();

// K-loop kept ROLLED (#pragma unroll 1): one copy of the 8-phase body in I$.
#define KLOOP_MAIN(tlim) \
  _Pragma("unroll 1") \
  for (int t = 0; t < (tlim); ++t) { \
    const int kt1 = 2 * t + 1, kt2 = 2 * t + 2, kt3 = 2 * t + 3; \
    LOAD_A(0, 0) LOAD_B(0, 0) \
    STAGE_A(1, 0, kt1) \
    PH_CORE(0, 0) PH_BAR() \
    LOAD_B(0, 1) \
    STAGE_A(1, 1, kt1) \
    PH_CORE(0, 1) PH_BAR() \
    LOAD_A(0, 1) \
    STAGE_B(0, 0, kt2) \
    PH_CORE(1, 1) PH_BAR() \
    STAGE_B(0, 1, kt2) \
    PH_CORE(1, 0) \
    WAIT_VM(4); \
    PH_BAR() \
    LOAD_A(1, 0) LOAD_B(1, 0) \
    STAGE_A(0, 0, kt2) \
    PH_CORE(0, 0) PH_BAR() \
    LOAD_B(1, 1) \
    STAGE_A(0, 1, kt2) \
    PH_CORE(0, 1) PH_BAR() \
    LOAD_A(1, 1) \
    STAGE_B(1, 0, kt3) \
    PH_CORE(1, 1) PH_BAR() \
    STAGE_B(1, 1, kt3) \
    PH_CORE(1, 0) \
    WAIT_VM(4); \
    PH_BAR() \
  }

#define KLOOP_LAST(ktL) { \
    LOAD_A(0, 0) LOAD_B(0, 0) \
    STAGE_A(1, 0, (ktL)) \
    PH_CORE(0, 0) PH_BAR() \
    LOAD_B(0, 1) \
    STAGE_A(1, 1, (ktL)) \
    PH_CORE(0, 1) PH_BAR() \
    LOAD_A(0, 1) \
    PH_CORE(1, 1) PH_BAR() \
    PH_CORE(1, 0) \
    WAIT_VM(0); \
    PH_BAR() \
    LOAD_A(1, 0) LOAD_B(1, 0) \
    PH_CORE(0, 0) PH_BAR() \
    LOAD_B(1, 1) \
    PH_CORE(0, 1) PH_BAR() \
    LOAD_A(1, 1) \
    PH_CORE(1, 1) PH_BAR() \
    PH_CORE(1, 0) \
    PH_BAR() \
  }

// ---------------- D2 kernel: outF = acc + bias ----------------
__global__ __launch_bounds__(512, 2)
void gemm256_f(const unsigned short* __restrict__ A,
               const unsigned short* __restrict__ W,
               const float* __restrict__ bias, int K, int N, int Ntiles,
               float* __restrict__ outF) {
  __shared__ __align__(16) char lds_[131072];

  const int tid  = threadIdx.x;
  const int lane = tid & 63;
  const int wv   = tid >> 6;
  const int wm   = wv >> 2;
  const int wn   = wv & 3;
  const int lr   = lane & 15;
  const int lq   = lane >> 4;
  const int rr8 = (wv << 3) + (lane >> 3);
  const int cc8 = ((lane & 7) ^ (lane >> 3)) << 3;

  const int nwg = gridDim.x;
  const int wg  = blockIdx.x;
  const int swz = (wg & 7) * (nwg >> 3) + (wg >> 3);
  const int tm  = swz / Ntiles;
  const int tn  = swz % Ntiles;
  const int m0  = tm * 256;
  const int n0  = tn * 256;

  f32x4 acc[8][4];
#pragma unroll
  for (int i = 0; i < 8; ++i)
#pragma unroll
    for (int j = 0; j < 4; ++j) acc[i][j] = (f32x4){0.f, 0.f, 0.f, 0.f};

  bf16x8 aR[2][4][2];
  bf16x8 bR[2][2][2];

  const int nIt = K >> 7;

  STAGE_B(0, 0, 0) STAGE_B(0, 1, 0) STAGE_A(0, 0, 0) STAGE_A(0, 1, 0)
  STAGE_B(1, 0, 1) STAGE_B(1, 1, 1)
  WAIT_VM(4);
  __builtin_amdgcn_s_barrier();

  KLOOP_MAIN(nIt - 1)
  KLOOP_LAST(2 * nIt - 1)

  float bj[4];
#pragma unroll
  for (int nf = 0; nf < 4; ++nf) bj[nf] = bias[n0 + wn * 64 + nf * 16 + lr];
#pragma unroll
  for (int mf = 0; mf < 8; ++mf) {
#pragma unroll
    for (int ii = 0; ii < 4; ++ii) {
      int row = m0 + wm * 128 + mf * 16 + lq * 4 + ii;
#pragma unroll
      for (int nf = 0; nf < 4; ++nf) {
        int col = n0 + wn * 64 + nf * 16 + lr;
        outF[(size_t)row * N + col] = acc[mf][nf][ii] + bj[nf];
      }
    }
  }
}

// ---------------- fused 8-step GRU persistent kernel, XCD-local ----------------
// grid = 256 (1 block/CU). bid%8 = XCD. All 8 blocks of an M-panel (tm) live
// on one XCD -> h exchange stays in that XCD's coherent L2 (fence-free; h
// rotates through fresh buffers; __syncthreads drains stores before signal).
// Step loop and K-loop kept ROLLED to keep code in I$ (R5 lesson).
__global__ __launch_bounds__(512, 2)
void gru_fused(unsigned short* __restrict__ H,        // [STEPS+1][HSZ]; H[0] = input
               const unsigned short* __restrict__ Wg,
               const float* __restrict__ biasg,
               float* __restrict__ traj,
               unsigned int* __restrict__ bar) {      // 8 counters, 128 B apart
  __shared__ __align__(16) char lds_[131072];

  const int tid  = threadIdx.x;
  const int lane = tid & 63;
  const int wv   = tid >> 6;
  const int wm   = wv >> 2;
  const int wn   = wv & 3;
  const int lr   = lane & 15;
  const int lq   = lane >> 4;
  const int rr8 = (wv << 3) + (lane >> 3);
  const int cc8 = ((lane & 7) ^ (lane >> 3)) << 3;

  const int K = LAT;                 // 512
  const unsigned short* W = Wg;

  const int bid = blockIdx.x;
  const int xcd = bid & 7;
  const int j   = bid >> 3;          // 0..31
  const int tm  = xcd + 8 * (j >> 3);
  const int tn  = j & 7;
  const int m0  = tm * 256;
  const int n0  = tn * 256;

  bf16x8 aR[2][4][2];
  bf16x8 bR[2][2][2];

  float bj[4];
#pragma unroll
  for (int nf = 0; nf < 4; ++nf) bj[nf] = biasg[n0 + wn * 64 + nf * 16 + lr];

  const unsigned short* A = H;       // step 0 input

  // prologue: ring = buf0{B,A} staged, buf1{B} in flight
  STAGE_B(0, 0, 0) STAGE_B(0, 1, 0) STAGE_A(0, 0, 0) STAGE_A(0, 1, 0)
  STAGE_B(1, 0, 1) STAGE_B(1, 1, 1)
  WAIT_VM(4);
  __builtin_amdgcn_s_barrier();

#pragma unroll 1
  for (int s = 0; s < STEPS; ++s) {
    unsigned short* hout = H + (size_t)(s + 1) * HSZ;

    f32x4 acc[8][4];
#pragma unroll
    for (int i = 0; i < 8; ++i)
#pragma unroll
      for (int jj = 0; jj < 4; ++jj) acc[i][jj] = (f32x4){0.f, 0.f, 0.f, 0.f};

    KLOOP_MAIN(3)          // nIt = 4 (K = 512), rolled: one body copy
    KLOOP_LAST(7)

    // ---- GRU gate epilogue ----
    {
      float* scr = (float*)lds_ + wv * 1088;
      const int latBase = tn * 64 + wn * 16;
      const int la = lane & 15;
      const int th = lane >> 4;
#pragma unroll 1
      for (int mf = 0; mf < 8; ++mf) {
        WAIT_LGKM0();
#pragma unroll
        for (int nf = 0; nf < 4; ++nf)
#pragma unroll
          for (int ii = 0; ii < 4; ++ii)
            scr[(lq * 4 + ii) * 68 + nf * 16 + lr] = acc[mf][nf][ii] + bj[nf];
        WAIT_LGKM0();
#pragma unroll
        for (int tb = 0; tb < 4; ++tb) {
          int tt = th * 4 + tb;
          int token = m0 + wm * 128 + mf * 16 + tt;
          f32x4 g = *(const f32x4*)(scr + tt * 68 + la * 4);  // [r̂, ẑ, i_n, h_n]
          int latc = latBase + la;
          float h  = bf16_to_f32(A[(size_t)token * LAT + latc]);
          float r  = sigmoidf_(g.x);
          float z  = sigmoidf_(g.y);
          float n  = tanhf_(g.z + r * g.w);
          float hn = (1.f - z) * n + z * h;
          hout[(size_t)token * LAT + latc] = f32_to_bf16_rne(hn);
          traj[(size_t)token * (STEPS * LAT) + s * LAT + latc] = hn;
        }
      }
    }

    if (s < STEPS - 1) {
      __syncthreads();                 // drains all waves' stores (vmcnt 0)
      // Wg is step-invariant: prefetch next step's buf0-B before the barrier
      STAGE_B(0, 0, 0) STAGE_B(0, 1, 0)
      if (tid == 0) {
        unsigned int* ctr = bar + xcd * 32;        // 128 B apart
        __hip_atomic_fetch_add(ctr, 1u, __ATOMIC_RELAXED, __HIP_MEMORY_SCOPE_AGENT);
        unsigned int target = 32u * (unsigned)(s + 1);
        while (__hip_atomic_load(ctr, __ATOMIC_RELAXED, __HIP_MEMORY_SCOPE_AGENT) < target)
          __builtin_amdgcn_s_sleep(2);
      }
      __syncthreads();
      A = hout;                        // next input = fresh buffer (first touch)
      STAGE_A(0, 0, 0) STAGE_A(0, 1, 0)
      STAGE_B(1, 0, 1) STAGE_B(1, 1, 1)
      WAIT_VM(4);
      __builtin_amdgcn_s_barrier();
    }
  }
}

// ---------------- launcher ----------------
extern "C" void kernel_launch(void* const* d_in, const int* in_sizes, int n_in,
                              void* d_out, int out_size, void* d_ws, size_t ws_size,
                              hipStream_t stream) {
  const float* hs  = (const float*)d_in[0];
  const float* We1 = (const float*)d_in[2];
  const float* be1 = (const float*)d_in[3];
  const float* We2 = (const float*)d_in[4];
  const float* be2 = (const float*)d_in[5];
  const float* Wd1 = (const float*)d_in[6];
  const float* bd1 = (const float*)d_in[7];
  const float* Wd2 = (const float*)d_in[8];
  const float* bd2 = (const float*)d_in[9];
  const float* wih = (const float*)d_in[10];
  const float* whh = (const float*)d_in[11];
  const float* bih = (const float*)d_in[12];
  const float* bhh = (const float*)d_in[13];

  char* ws = (char*)d_ws;
  unsigned short* A0    = (unsigned short*)(ws + 0);          // 33,554,432 B
  unsigned short* We1b  = (unsigned short*)(ws + 33554432);   //  4,194,304
  unsigned short* We2b  = (unsigned short*)(ws + 37748736);   //  1,048,576
  unsigned short* Wd1b  = (unsigned short*)(ws + 38797312);   //  1,048,576
  unsigned short* Wd2b  = (unsigned short*)(ws + 39845888);   //  4,194,304
  unsigned short* Wg    = (unsigned short*)(ws + 44040192);   //  2,097,152
  float*          biasg = (float*)         (ws + 46137344);   //      8,192
  unsigned short* X1    = (unsigned short*)(ws + 46145536);   // 16,777,216
  unsigned short* H     = (unsigned short*)(ws + 62922752);   // 9 x 8,388,608
  unsigned int*   bar   = (unsigned int*)  (ws + 138420224);  //      1,024
  unsigned short* X2    = A0;                                 // A0 dead after E1

  float* dec  = (float*)d_out;
  float* traj = (float*)d_out + DEC_ELEMS;

  hipMemsetAsync(bar, 0, 1024, stream);
  k_prep<<<2048, 256, 0, stream>>>(hs, We1, We2, Wd1, Wd2, A0, We1b, We2b, Wd1b, Wd2b);
  k_gru_pack<<<GCOLS, 128, 0, stream>>>(wih, whh, bih, bhh, Wg, biasg);

  // encode
  gemm_bt<0><<<dim3(TOKENS / MWG, LAT2 / NWG), dim3(256), 0, stream>>>(
      A0, We1b, be1, HID, LAT2, X1);
  gemm_bt<1><<<dim3(TOKENS / MWG, LAT / NWG), dim3(256), 0, stream>>>(
      X1, We2b, be2, LAT2, LAT, H);                 // latent -> H[0]
  // 8 fused GRU steps (persistent, XCD-local exchange, fence-free)
  gru_fused<<<256, 512, 0, stream>>>(H, Wg, biasg, traj, bar);
  // decode (final latent in H[8])
  gemm_bt<0><<<dim3(TOKENS / MWG, LAT2 / NWG), dim3(256), 0, stream>>>(
      H + (size_t)STEPS * HSZ, Wd1b, bd1, LAT, LAT2, X2);
  gemm256_f<<<256, 512, 0, stream>>>(X2, Wd2b, bd2, LAT2, HID, 8, dec);
}

// Round 7
// 441.534 us; speedup vs baseline: 1.7745x; 1.7745x over previous
//
#include <hip/hip_runtime.h>
#include <hip/hip_bf16.h>
#include <cstdint>
#include <cstddef>

// ---------------- problem constants ----------------
#define TOKENS   8192          // B*S
#define HID      2048
#define LAT      512
#define LAT2     1024
#define GCOLS    2048          // 4 gates * LAT (packed col = 4*l + g)
#define STEPS    8
#define DEC_ELEMS (TOKENS*HID)

typedef __attribute__((ext_vector_type(8))) __bf16 bf16x8;
typedef __attribute__((ext_vector_type(4))) float  f32x4;
typedef __attribute__((ext_vector_type(8))) unsigned short u16x8;

// ---------------- helpers ----------------
__device__ __forceinline__ unsigned short f32_to_bf16_rne(float f) {
  unsigned int u = __float_as_uint(f);
  unsigned int r = (u + 0x7FFFu + ((u >> 16) & 1u)) >> 16;
  return (unsigned short)r;
}
__device__ __forceinline__ float bf16_to_f32(unsigned short u) {
  return __uint_as_float(((unsigned int)u) << 16);
}

__device__ __forceinline__ float sigmoidf_(float x) {
  if (x >= 0.f) { float e = __expf(-x); return 1.f / (1.f + e); }
  float e = __expf(x); return e / (1.f + e);
}
__device__ __forceinline__ float tanhf_(float x) {
  float ax = fabsf(x);
  float e  = __expf(-2.f * ax);
  float t  = (1.f - e) / (1.f + e);
  return copysignf(t, x);
}

__device__ __forceinline__ void gl_lds16(const void* g, void* l) {
  __builtin_amdgcn_global_load_lds(
      (const __attribute__((address_space(1))) void*)g,
      (__attribute__((address_space(3))) void*)l, 16, 0, 0);
}

// ---------------- prep kernels ----------------
// Weight casts only (hs cast is fused into E1's A-staging).
__global__ void k_prep_w(const float* __restrict__ We1, const float* __restrict__ We2,
                         const float* __restrict__ Wd1, const float* __restrict__ Wd2,
                         unsigned short* __restrict__ We1b, unsigned short* __restrict__ We2b,
                         unsigned short* __restrict__ Wd1b, unsigned short* __restrict__ Wd2b) {
  const int total = 1310720;   // float4 count: 524288+131072+131072+524288
  int i = blockIdx.x * blockDim.x + threadIdx.x;
  int stride = gridDim.x * blockDim.x;
  for (; i < total; i += stride) {
    const float* s; unsigned short* d; int j;
    if (i < 524288)       { s = We1; d = We1b; j = i; }
    else if (i < 655360)  { s = We2; d = We2b; j = i - 524288; }
    else if (i < 786432)  { s = Wd1; d = Wd1b; j = i - 655360; }
    else                  { s = Wd2; d = Wd2b; j = i - 786432; }
    float4 v = ((const float4*)s)[j];
    ushort4 o;
    o.x = f32_to_bf16_rne(v.x);
    o.y = f32_to_bf16_rne(v.y);
    o.z = f32_to_bf16_rne(v.z);
    o.w = f32_to_bf16_rne(v.w);
    ((ushort4*)d)[j] = o;
  }
}

// Pack GRU weights: output row gc = 4*l + g, g in {0:r-sum, 1:z-sum, 2:i_n, 3:h_n}
__global__ void k_gru_pack(const float* __restrict__ wih, const float* __restrict__ whh,
                           const float* __restrict__ bih, const float* __restrict__ bhh,
                           unsigned short* __restrict__ Wg, float* __restrict__ biasg) {
  int gc = blockIdx.x;
  int l  = gc >> 2;
  int g  = gc & 3;
  int row = (g == 0) ? l : (g == 1) ? (512 + l) : (1024 + l);
  for (int c = threadIdx.x; c < LAT; c += blockDim.x) {
    float v;
    if (g <= 1)      v = wih[row * LAT + c] + whh[row * LAT + c];
    else if (g == 2) v = wih[row * LAT + c];
    else             v = whh[row * LAT + c];
    Wg[(size_t)gc * LAT + c] = f32_to_bf16_rne(v);
  }
  if (threadIdx.x == 0) {
    float b;
    if (g <= 1)      b = bih[row] + bhh[row];
    else if (g == 2) b = bih[row];
    else             b = bhh[row];
    biasg[gc] = b;
  }
}

// =======================================================================
// 128x128 2-barrier kernel (E1, E2, D1)
// EPI 0: outB = bf16(relu(acc+bias));  EPI 1: outB = bf16(acc+bias)
// A32 1: A operand is fp32 in HBM; cast fused into reg-staged LDS write.
// =======================================================================
#define MWG 128
#define NWG 128
#define KTILE 64

template <int EPI, int A32>
__global__ __launch_bounds__(256)
void gemm_bt(const void* __restrict__ Ap,
             const unsigned short* __restrict__ W,
             const float* __restrict__ bias,
             int K, int N,
             unsigned short* __restrict__ outB) {
  __shared__ __align__(16) char smem[2 * MWG * KTILE * 2];
  unsigned short* As = (unsigned short*)smem;
  unsigned short* Bs = As + MWG * KTILE;

  const int tid  = threadIdx.x;
  const int lane = tid & 63;
  const int wv   = tid >> 6;
  const int wr   = wv >> 1;
  const int wc   = wv & 1;
  const int m0   = blockIdx.x * MWG;
  const int n0   = blockIdx.y * NWG;

  const int lr = lane & 15;
  const int lq = lane >> 4;
  const int srow = lane >> 3;
  const int scol = (lane & 7) * 8;

  f32x4 acc[4][4];
#pragma unroll
  for (int i = 0; i < 4; ++i)
#pragma unroll
    for (int j = 0; j < 4; ++j) acc[i][j] = (f32x4){0.f, 0.f, 0.f, 0.f};

  const unsigned short* Ab = (const unsigned short*)Ap + (size_t)m0 * K;
  const float*          Af = (const float*)Ap + (size_t)m0 * K;
  const unsigned short* Wb = W + (size_t)n0 * K;

  const int KT = K / KTILE;
  for (int kt = 0; kt < KT; ++kt) {
    const int k0 = kt * KTILE;
#pragma unroll
    for (int q = 0; q < 4; ++q) {
      int row = 32 * wv + 8 * q + srow;
      if constexpr (!A32)
        gl_lds16(Ab + (size_t)row * K + k0 + scol, As + (32 * wv + 8 * q) * KTILE);
      gl_lds16(Wb + (size_t)row * K + k0 + scol, Bs + (32 * wv + 8 * q) * KTILE);
    }
    if constexpr (A32) {
      // reg-staged A: fp32 load -> bf16 cvt -> ds_write_b128 (same linear layout)
#pragma unroll
      for (int q = 0; q < 4; ++q) {
        int row = 32 * wv + 8 * q + srow;
        const float* src = Af + (size_t)row * K + k0 + scol;
        float4 v0 = *(const float4*)src;
        float4 v1 = *(const float4*)(src + 4);
        u16x8 o;
        o[0] = f32_to_bf16_rne(v0.x); o[1] = f32_to_bf16_rne(v0.y);
        o[2] = f32_to_bf16_rne(v0.z); o[3] = f32_to_bf16_rne(v0.w);
        o[4] = f32_to_bf16_rne(v1.x); o[5] = f32_to_bf16_rne(v1.y);
        o[6] = f32_to_bf16_rne(v1.z); o[7] = f32_to_bf16_rne(v1.w);
        *(u16x8*)(As + (32 * wv + 8 * q) * KTILE + lane * 8) = o;
      }
    }
    __syncthreads();
#pragma unroll
    for (int kk = 0; kk < KTILE; kk += 32) {
      bf16x8 af[4], bf[4];
#pragma unroll
      for (int i = 0; i < 4; ++i)
        af[i] = *(const bf16x8*)(As + (wr * 64 + i * 16 + lr) * KTILE + kk + lq * 8);
#pragma unroll
      for (int j = 0; j < 4; ++j)
        bf[j] = *(const bf16x8*)(Bs + (wc * 64 + j * 16 + lr) * KTILE + kk + lq * 8);
#pragma unroll
      for (int i = 0; i < 4; ++i)
#pragma unroll
        for (int j = 0; j < 4; ++j)
          acc[i][j] = __builtin_amdgcn_mfma_f32_16x16x32_bf16(af[i], bf[j], acc[i][j], 0, 0, 0);
    }
    __syncthreads();
  }

  float bj[4];
#pragma unroll
  for (int j = 0; j < 4; ++j) bj[j] = bias[n0 + wc * 64 + j * 16 + lr];
#pragma unroll
  for (int i = 0; i < 4; ++i) {
#pragma unroll
    for (int ii = 0; ii < 4; ++ii) {
      int row = m0 + wr * 64 + i * 16 + 4 * lq + ii;
#pragma unroll
      for (int j = 0; j < 4; ++j) {
        int col = n0 + wc * 64 + j * 16 + lr;
        float v = acc[i][j][ii] + bj[j];
        if constexpr (EPI == 0) {
          outB[(size_t)row * N + col] = f32_to_bf16_rne(fmaxf(v, 0.f));
        } else {
          outB[(size_t)row * N + col] = f32_to_bf16_rne(v);
        }
      }
    }
  }
}

// =======================================================================
// 256x256 8-phase pipeline pieces (T2 swizzle + T3/T4 counted vmcnt + T5)
// =======================================================================

#define WAIT_LGKM0() asm volatile("s_waitcnt lgkmcnt(0)" ::: "memory")
#define WAIT_VM(n)   asm volatile("s_waitcnt vmcnt(" #n ")" ::: "memory")

#define LOAD_A(buf, mh) { \
  const int baseA = (buf)*65536 + wm*16384; \
  _Pragma("unroll") for (int m4 = 0; m4 < 4; ++m4) \
  _Pragma("unroll") for (int kki = 0; kki < 2; ++kki) { \
    int rl = (mh)*64 + m4*16 + lr; \
    int off = (rl*128 + kki*64 + lq*16) ^ ((rl & 7) << 4); \
    aR[mh][m4][kki] = *(const bf16x8*)(lds_ + baseA + off); } }

#define LOAD_B(buf, nh) { \
  const int baseB = (buf)*65536 + 32768 + (wn >> 1)*16384; \
  _Pragma("unroll") for (int n2 = 0; n2 < 2; ++n2) \
  _Pragma("unroll") for (int kki = 0; kki < 2; ++kki) { \
    int rl = (wn & 1)*64 + ((nh)*2 + n2)*16 + lr; \
    int off = (rl*128 + kki*64 + lq*16) ^ ((rl & 7) << 4); \
    bR[nh][n2][kki] = *(const bf16x8*)(lds_ + baseB + off); } }

#define STAGE_A(buf, half, kt) { \
  const unsigned short* gp = A + (size_t)(m0 + (half)*128 + rr8)*K + (size_t)(kt)*64 + cc8; \
  char* dp = lds_ + (buf)*65536 + (half)*16384 + (wv << 10); \
  gl_lds16(gp, dp); \
  gl_lds16(gp + (size_t)64*K, dp + 8192); }

#define STAGE_B(buf, half, kt) { \
  const unsigned short* gp = W + (size_t)(n0 + (half)*128 + rr8)*K + (size_t)(kt)*64 + cc8; \
  char* dp = lds_ + (buf)*65536 + 32768 + (half)*16384 + (wv << 10); \
  gl_lds16(gp, dp); \
  gl_lds16(gp + (size_t)64*K, dp + 8192); }

#define MFMAQ(mh, nh) \
  _Pragma("unroll") for (int kki = 0; kki < 2; ++kki) \
  _Pragma("unroll") for (int n2 = 0; n2 < 2; ++n2) \
  _Pragma("unroll") for (int m4 = 0; m4 < 4; ++m4) \
    acc[(mh)*4 + m4][(nh)*2 + n2] = __builtin_amdgcn_mfma_f32_16x16x32_bf16( \
        aR[mh][m4][kki], bR[nh][n2][kki], acc[(mh)*4 + m4][(nh)*2 + n2], 0, 0, 0);

#define PH_CORE(mh, nh) \
  __builtin_amdgcn_s_barrier(); \
  WAIT_LGKM0(); \
  __builtin_amdgcn_sched_barrier(0); \
  __builtin_amdgcn_s_setprio(1); \
  MFMAQ(mh, nh); \
  __builtin_amdgcn_sched_barrier(0); \
  __builtin_amdgcn_s_setprio(0);

#define PH_BAR() __builtin_amdgcn_s_barrier();

#define KLOOP_MAIN(tlim) \
  _Pragma("unroll 1") \
  for (int t = 0; t < (tlim); ++t) { \
    const int kt1 = 2 * t + 1, kt2 = 2 * t + 2, kt3 = 2 * t + 3; \
    LOAD_A(0, 0) LOAD_B(0, 0) \
    STAGE_A(1, 0, kt1) \
    PH_CORE(0, 0) PH_BAR() \
    LOAD_B(0, 1) \
    STAGE_A(1, 1, kt1) \
    PH_CORE(0, 1) PH_BAR() \
    LOAD_A(0, 1) \
    STAGE_B(0, 0, kt2) \
    PH_CORE(1, 1) PH_BAR() \
    STAGE_B(0, 1, kt2) \
    PH_CORE(1, 0) \
    WAIT_VM(4); \
    PH_BAR() \
    LOAD_A(1, 0) LOAD_B(1, 0) \
    STAGE_A(0, 0, kt2) \
    PH_CORE(0, 0) PH_BAR() \
    LOAD_B(1, 1) \
    STAGE_A(0, 1, kt2) \
    PH_CORE(0, 1) PH_BAR() \
    LOAD_A(1, 1) \
    STAGE_B(1, 0, kt3) \
    PH_CORE(1, 1) PH_BAR() \
    STAGE_B(1, 1, kt3) \
    PH_CORE(1, 0) \
    WAIT_VM(4); \
    PH_BAR() \
  }

#define KLOOP_LAST(ktL) { \
    LOAD_A(0, 0) LOAD_B(0, 0) \
    STAGE_A(1, 0, (ktL)) \
    PH_CORE(0, 0) PH_BAR() \
    LOAD_B(0, 1) \
    STAGE_A(1, 1, (ktL)) \
    PH_CORE(0, 1) PH_BAR() \
    LOAD_A(0, 1) \
    PH_CORE(1, 1) PH_BAR() \
    PH_CORE(1, 0) \
    WAIT_VM(0); \
    PH_BAR() \
    LOAD_A(1, 0) LOAD_B(1, 0) \
    PH_CORE(0, 0) PH_BAR() \
    LOAD_B(1, 1) \
    PH_CORE(0, 1) PH_BAR() \
    LOAD_A(1, 1) \
    PH_CORE(1, 1) PH_BAR() \
    PH_CORE(1, 0) \
    PH_BAR() \
  }

// ---------------- D2 kernel: outF = acc + bias ----------------
__global__ __launch_bounds__(512, 2)
void gemm256_f(const unsigned short* __restrict__ A,
               const unsigned short* __restrict__ W,
               const float* __restrict__ bias, int K, int N, int Ntiles,
               float* __restrict__ outF) {
  __shared__ __align__(16) char lds_[131072];

  const int tid  = threadIdx.x;
  const int lane = tid & 63;
  const int wv   = tid >> 6;
  const int wm   = wv >> 2;
  const int wn   = wv & 3;
  const int lr   = lane & 15;
  const int lq   = lane >> 4;
  const int rr8 = (wv << 3) + (lane >> 3);
  const int cc8 = ((lane & 7) ^ (lane >> 3)) << 3;

  const int nwg = gridDim.x;
  const int wg  = blockIdx.x;
  const int swz = (wg & 7) * (nwg >> 3) + (wg >> 3);
  const int tm  = swz / Ntiles;
  const int tn  = swz % Ntiles;
  const int m0  = tm * 256;
  const int n0  = tn * 256;

  f32x4 acc[8][4];
#pragma unroll
  for (int i = 0; i < 8; ++i)
#pragma unroll
    for (int j = 0; j < 4; ++j) acc[i][j] = (f32x4){0.f, 0.f, 0.f, 0.f};

  bf16x8 aR[2][4][2];
  bf16x8 bR[2][2][2];

  const int nIt = K >> 7;

  STAGE_B(0, 0, 0) STAGE_B(0, 1, 0) STAGE_A(0, 0, 0) STAGE_A(0, 1, 0)
  STAGE_B(1, 0, 1) STAGE_B(1, 1, 1)
  WAIT_VM(4);
  __builtin_amdgcn_s_barrier();

  KLOOP_MAIN(nIt - 1)
  KLOOP_LAST(2 * nIt - 1)

  float bj[4];
#pragma unroll
  for (int nf = 0; nf < 4; ++nf) bj[nf] = bias[n0 + wn * 64 + nf * 16 + lr];
#pragma unroll
  for (int mf = 0; mf < 8; ++mf) {
#pragma unroll
    for (int ii = 0; ii < 4; ++ii) {
      int row = m0 + wm * 128 + mf * 16 + lq * 4 + ii;
#pragma unroll
      for (int nf = 0; nf < 4; ++nf) {
        int col = n0 + wn * 64 + nf * 16 + lr;
        outF[(size_t)row * N + col] = acc[mf][nf][ii] + bj[nf];
      }
    }
  }
}

// ---------------- GRU step kernel (one launch per step) ----------------
__global__ __launch_bounds__(512, 2)
void gemm256_gru(const unsigned short* __restrict__ A,   // h_in bf16 [TOKENS x LAT]
                 const unsigned short* __restrict__ W,   // Wg [GCOLS x LAT]
                 const float* __restrict__ bias,         // biasg
                 int K, int N, int Ntiles,
                 unsigned short* __restrict__ outB,      // h_out bf16
                 const unsigned short* __restrict__ hInB,
                 float* __restrict__ traj,
                 int step) {
  __shared__ __align__(16) char lds_[131072];

  const int tid  = threadIdx.x;
  const int lane = tid & 63;
  const int wv   = tid >> 6;
  const int wm   = wv >> 2;
  const int wn   = wv & 3;
  const int lr   = lane & 15;
  const int lq   = lane >> 4;
  const int rr8 = (wv << 3) + (lane >> 3);
  const int cc8 = ((lane & 7) ^ (lane >> 3)) << 3;

  const int nwg = gridDim.x;
  const int wg  = blockIdx.x;
  const int swz = (wg & 7) * (nwg >> 3) + (wg >> 3);
  const int tm  = swz / Ntiles;
  const int tn  = swz % Ntiles;
  const int m0  = tm * 256;
  const int n0  = tn * 256;

  f32x4 acc[8][4];
#pragma unroll
  for (int i = 0; i < 8; ++i)
#pragma unroll
    for (int j = 0; j < 4; ++j) acc[i][j] = (f32x4){0.f, 0.f, 0.f, 0.f};

  bf16x8 aR[2][4][2];
  bf16x8 bR[2][2][2];

  const int nIt = K >> 7;

  STAGE_B(0, 0, 0) STAGE_B(0, 1, 0) STAGE_A(0, 0, 0) STAGE_A(0, 1, 0)
  STAGE_B(1, 0, 1) STAGE_B(1, 1, 1)
  WAIT_VM(4);
  __builtin_amdgcn_s_barrier();

  KLOOP_MAIN(nIt - 1)
  KLOOP_LAST(2 * nIt - 1)

  float bj[4];
#pragma unroll
  for (int nf = 0; nf < 4; ++nf) bj[nf] = bias[n0 + wn * 64 + nf * 16 + lr];

  // GRU gate epilogue: wave tile = 128 tokens x 64 gate cols = 16 latents
  float* scr = (float*)lds_ + wv * 1088;      // 16 x 68 floats per wave
  const int latBase = tn * 64 + wn * 16;
  const int la = lane & 15;
  const int th = lane >> 4;
#pragma unroll
  for (int mf = 0; mf < 8; ++mf) {
    WAIT_LGKM0();
#pragma unroll
    for (int nf = 0; nf < 4; ++nf)
#pragma unroll
      for (int ii = 0; ii < 4; ++ii)
        scr[(lq * 4 + ii) * 68 + nf * 16 + lr] = acc[mf][nf][ii] + bj[nf];
    WAIT_LGKM0();
#pragma unroll
    for (int tb = 0; tb < 4; ++tb) {
      int tt = th * 4 + tb;
      int token = m0 + wm * 128 + mf * 16 + tt;
      f32x4 g = *(const f32x4*)(scr + tt * 68 + la * 4);  // [r̂, ẑ, i_n, h_n]
      int latc = latBase + la;
      float h  = bf16_to_f32(hInB[(size_t)token * LAT + latc]);
      float r  = sigmoidf_(g.x);
      float z  = sigmoidf_(g.y);
      float n  = tanhf_(g.z + r * g.w);
      float hn = (1.f - z) * n + z * h;
      outB[(size_t)token * LAT + latc] = f32_to_bf16_rne(hn);
      traj[(size_t)token * (STEPS * LAT) + step * LAT + latc] = hn;
    }
  }
}

// ---------------- launcher ----------------
extern "C" void kernel_launch(void* const* d_in, const int* in_sizes, int n_in,
                              void* d_out, int out_size, void* d_ws, size_t ws_size,
                              hipStream_t stream) {
  const float* hs  = (const float*)d_in[0];
  const float* We1 = (const float*)d_in[2];
  const float* be1 = (const float*)d_in[3];
  const float* We2 = (const float*)d_in[4];
  const float* be2 = (const float*)d_in[5];
  const float* Wd1 = (const float*)d_in[6];
  const float* bd1 = (const float*)d_in[7];
  const float* Wd2 = (const float*)d_in[8];
  const float* bd2 = (const float*)d_in[9];
  const float* wih = (const float*)d_in[10];
  const float* whh = (const float*)d_in[11];
  const float* bih = (const float*)d_in[12];
  const float* bhh = (const float*)d_in[13];

  char* ws = (char*)d_ws;
  unsigned short* X2    = (unsigned short*)(ws + 0);          // 16,777,216 B
  unsigned short* We1b  = (unsigned short*)(ws + 33554432);   //  4,194,304
  unsigned short* We2b  = (unsigned short*)(ws + 37748736);   //  1,048,576
  unsigned short* Wd1b  = (unsigned short*)(ws + 38797312);   //  1,048,576
  unsigned short* Wd2b  = (unsigned short*)(ws + 39845888);   //  4,194,304
  unsigned short* Wg    = (unsigned short*)(ws + 44040192);   //  2,097,152
  float*          biasg = (float*)         (ws + 46137344);   //      8,192
  unsigned short* X1    = (unsigned short*)(ws + 46145536);   // 16,777,216
  unsigned short* Lb0   = (unsigned short*)(ws + 62922752);   //  8,388,608
  unsigned short* Lb1   = (unsigned short*)(ws + 71311360);   //  8,388,608

  float* dec  = (float*)d_out;
  float* traj = (float*)d_out + DEC_ELEMS;

  // prep: weight casts + GRU weight packing (hs cast fused into E1)
  k_prep_w<<<1024, 256, 0, stream>>>(We1, We2, Wd1, Wd2, We1b, We2b, Wd1b, Wd2b);
  k_gru_pack<<<GCOLS, 128, 0, stream>>>(wih, whh, bih, bhh, Wg, biasg);

  // encode: E1 reads fp32 hs directly (A32 reg-staged cast)
  gemm_bt<0, 1><<<dim3(TOKENS / MWG, LAT2 / NWG), dim3(256), 0, stream>>>(
      hs, We1b, be1, HID, LAT2, X1);
  gemm_bt<1, 0><<<dim3(TOKENS / MWG, LAT / NWG), dim3(256), 0, stream>>>(
      X1, We2b, be2, LAT2, LAT, Lb0);
  // 8 GRU steps (double-buffered bf16 latent), 256^2 8-phase fused-gate kernel
  for (int s = 0; s < STEPS; ++s) {
    const unsigned short* lbi = (s & 1) ? Lb1 : Lb0;
    unsigned short*       lbo = (s & 1) ? Lb0 : Lb1;
    gemm256_gru<<<256, 512, 0, stream>>>(lbi, Wg, biasg, LAT, GCOLS, 8,
                                         lbo, lbi, traj, s);
  }
  // decode (after 8 steps latent is in Lb0)
  gemm_bt<0, 0><<<dim3(TOKENS / MWG, LAT2 / NWG), dim3(256), 0, stream>>>(
      Lb0, Wd1b, bd1, LAT, LAT2, X2);
  gemm256_f<<<256, 512, 0, stream>>>(X2, Wd2b, bd2, LAT2, HID, 8, dec);
}